// Round 1
// baseline (756.715 us; speedup 1.0000x reference)
//
#include <hip/hip_runtime.h>
#include <math.h>

#define GRIDN    128
#define NRAYS    16384
#define STEPSZ   0.5f
#define MAXSTEPS 320
#define SEGS     64
#define SPS      (MAXSTEPS / SEGS)   // 5 steps per segment
#define RPB      4                   // rays per block (1 wave = 1 ray)
#define TPB      (RPB * 64)          // 256 threads
#define NVOX     (GRIDN * GRIDN * GRIDN)
// fp16 record: 32 halves (64 B) per VOXEL: [0]=density, [1..27]=sh, pad.
// Voxel-indexed (links folded in at repack time); empty voxels = zero record.
#define PACK_BYTES ((size_t)(NVOX + 1) * 64)

typedef _Float16 half8 __attribute__((ext_vector_type(8)));

// ---------------------------------------------------------------------------
// Prologue: voxel-indexed repack. Each wave handles 64 consecutive voxels:
// coalesced span-read of the 64 candidate data rows into LDS (rows are a
// superset of what the links select; density/sh have NVOX rows so the span
// read is always in-bounds), then each lane picks its row via links[v].
// Out-of-span links (impossible for identity-style tables, legal in general)
// fall back to a per-lane gather. Empty voxels write a zero record, which
// makes the march kernel's fetch unconditional.
// ---------------------------------------------------------------------------
__global__ __launch_bounds__(256, 5)
void repack_kernel(const int*   __restrict__ links,
                   const float* __restrict__ density,
                   const float* __restrict__ sh,
                   _Float16*    __restrict__ pack)
{
    __shared__ float buf[4][64 * 27];   // 27648 B/block
    const int lane  = threadIdx.x & 63;
    const int wv    = threadIdx.x >> 6;
    const int vbase = (blockIdx.x * 4 + wv) * 64;

    const float* src = sh + (size_t)vbase * 27;
    float* b = buf[wv];
    #pragma unroll
    for (int j = 0; j < 27; j++)
        b[j * 64 + lane] = src[j * 64 + lane];   // coalesced flat copy of 64 rows

    const int v   = vbase + lane;
    const int lnk = links[v];                    // coalesced
    float dens = 0.0f;
    if (lnk >= 0) dens = density[lnk];
    __syncthreads();

    __align__(16) _Float16 rec[32];
    #pragma unroll
    for (int k = 0; k < 32; k++) rec[k] = (_Float16)0.0f;

    if (lnk >= 0) {
        rec[0] = (_Float16)dens;
        if (lnk >= vbase && lnk < vbase + 64) {
            const float* myrow = b + (lnk - vbase) * 27;  // stride 27: conflict-free
            #pragma unroll
            for (int k = 0; k < 27; k++) rec[1 + k] = (_Float16)myrow[k];
        } else {
            const float* row = sh + (size_t)lnk * 27;     // rare general-case gather
            #pragma unroll
            for (int k = 0; k < 27; k++) rec[1 + k] = (_Float16)row[k];
        }
    }

    uint4* dst = (uint4*)(pack + (size_t)v * 32);
    const uint4* rp = (const uint4*)rec;
    dst[0] = rp[0]; dst[1] = rp[1]; dst[2] = rp[2]; dst[3] = rp[3];
}

// ---------------------------------------------------------------------------
// March: one wave = one ray, lane = segment (5 steps each). Single memory
// round-trip per cell-change (voxel-indexed pack, no links gather). Segment
// stitching via wave-level prefix scan of log-transmittance — no LDS.
// ---------------------------------------------------------------------------
template <bool PACKED>
__global__ __launch_bounds__(TPB, 8)
void march_kernel(const float* __restrict__ origins,
                  const float* __restrict__ dirs,
                  const int*   __restrict__ links,
                  const float* __restrict__ density,
                  const float* __restrict__ sh,
                  const _Float16* __restrict__ pack,
                  float* __restrict__ out)
{
    const int tid  = threadIdx.x;
    const int lane = tid & 63;          // segment index
    const int r    = tid >> 6;          // ray slot within block
    const int ray  = blockIdx.x * RPB + r;

    // ---- ray setup ----
    const float owx = origins[ray * 3 + 0];
    const float owy = origins[ray * 3 + 1];
    const float owz = origins[ray * 3 + 2];
    const float dwx = dirs[ray * 3 + 0];
    const float dwy = dirs[ray * 3 + 1];
    const float dwz = dirs[ray * 3 + 2];

    const float invn = 1.0f / sqrtf(dwx * dwx + dwy * dwy + dwz * dwz);
    const float vx = dwx * invn, vy = dwy * invn, vz = dwz * invn;

    const float ox = 63.5f + owx * 64.0f;
    const float oy = 63.5f + owy * 64.0f;
    const float oz = 63.5f + owz * 64.0f;

    const float sxx = vx * 64.0f, syy = vy * 64.0f, szz = vz * 64.0f;
    const float ds  = 1.0f / sqrtf(sxx * sxx + syy * syy + szz * szz);
    const float dx = sxx * ds, dy = syy * ds, dz = szz * ds;

    float shm[9];
    shm[0] = 0.28209479177387814f;
    shm[1] = -0.4886025119029199f * vy;
    shm[2] =  0.4886025119029199f * vz;
    shm[3] = -0.4886025119029199f * vx;
    shm[4] =  1.0925484305920792f * vx * vy;
    shm[5] = -1.0925484305920792f * vy * vz;
    shm[6] =  0.31539156525252005f * (2.0f * vz * vz - vx * vx - vy * vy);
    shm[7] = -1.0925484305920792f * vx * vz;
    shm[8] =  0.5462742152960396f * (vx * vx - vy * vy);

    float t0 = 0.0f, tmax = 1e9f;
    {
        const float o3[3] = { ox, oy, oz };
        const float d3[3] = { dx, dy, dz };
        #pragma unroll
        for (int a = 0; a < 3; a++) {
            if (d3[a] != 0.0f) {
                float inv = 1.0f / d3[a];
                float ta = (-0.5f  - o3[a]) * inv;
                float tb = (127.5f - o3[a]) * inv;
                t0   = fmaxf(t0,   fminf(ta, tb));
                tmax = fminf(tmax, fmaxf(ta, tb));
            }
        }
    }

    float ll = 0.0f;           // segment-local log transmittance
    float light = 1.0f;
    float aR = 0, aG = 0, aB = 0, aA = 0, aD1 = 0, aD2 = 0;

    int cached_cell = -1;
    float csig[8], cr0[8], cr1[8], cr2[8];

    const int k0 = lane * SPS;
    for (int i = 0; i < SPS; i++) {
        const float t = t0 + (float)(k0 + i) * STEPSZ;
        if (t > tmax) break;

        float px = fminf(fmaxf(ox + t * dx, 0.0f), 127.0f);
        float py = fminf(fmaxf(oy + t * dy, 0.0f), 127.0f);
        float pz = fminf(fmaxf(oz + t * dz, 0.0f), 127.0f);
        const int lx = min(max((int)px, 0), 126);
        const int ly = min(max((int)py, 0), 126);
        const int lz = min(max((int)pz, 0), 126);
        const float fx = px - (float)lx;
        const float fy = py - (float)ly;
        const float fz = pz - (float)lz;

        const int cell = (lx << 14) | (ly << 7) | lz;
        if (cell != cached_cell) {
            cached_cell = cell;
            if (PACKED) {
                #pragma unroll
                for (int c = 0; c < 8; c++) {
                    const int cdx = (c >> 2) & 1, cdy = (c >> 1) & 1, cdz = c & 1;
                    const int vox = cell + (cdx << 14) + (cdy << 7) + cdz;
                    const half8* pr = (const half8*)(pack + (size_t)vox * 32);
                    const half8 h0 = pr[0], h1 = pr[1], h2 = pr[2], h3 = pr[3];
                    csig[c] = (float)h0[0];
                    cr0[c] = shm[0]*(float)h0[1] + shm[1]*(float)h0[2] + shm[2]*(float)h0[3]
                           + shm[3]*(float)h0[4] + shm[4]*(float)h0[5] + shm[5]*(float)h0[6]
                           + shm[6]*(float)h0[7] + shm[7]*(float)h1[0] + shm[8]*(float)h1[1];
                    cr1[c] = shm[0]*(float)h1[2] + shm[1]*(float)h1[3] + shm[2]*(float)h1[4]
                           + shm[3]*(float)h1[5] + shm[4]*(float)h1[6] + shm[5]*(float)h1[7]
                           + shm[6]*(float)h2[0] + shm[7]*(float)h2[1] + shm[8]*(float)h2[2];
                    cr2[c] = shm[0]*(float)h2[3] + shm[1]*(float)h2[4] + shm[2]*(float)h2[5]
                           + shm[3]*(float)h2[6] + shm[4]*(float)h2[7] + shm[5]*(float)h3[0]
                           + shm[6]*(float)h3[1] + shm[7]*(float)h3[2] + shm[8]*(float)h3[3];
                }
            } else {
                #pragma unroll
                for (int c = 0; c < 8; c++) {
                    const int cdx = (c >> 2) & 1, cdy = (c >> 1) & 1, cdz = c & 1;
                    const int idx = cell + (cdx << 14) + (cdy << 7) + cdz;
                    const int lnk = links[idx];
                    float sg = 0, q0 = 0, q1 = 0, q2 = 0;
                    if (lnk >= 0) {
                        sg = density[lnk];
                        const float* row = sh + (size_t)lnk * 27;
                        #pragma unroll
                        for (int k = 0; k < 9; k++) {
                            const float m = shm[k];
                            q0 += m * row[k];
                            q1 += m * row[9 + k];
                            q2 += m * row[18 + k];
                        }
                    }
                    csig[c] = sg; cr0[c] = q0; cr1[c] = q1; cr2[c] = q2;
                }
            }
        }

        const float gx1 = fx, gx0 = 1.0f - fx;
        const float gy1 = fy, gy0 = 1.0f - fy;
        const float gz1 = fz, gz0 = 1.0f - fz;
        float w[8];
        w[0] = gx0*gy0*gz0; w[1] = gx0*gy0*gz1; w[2] = gx0*gy1*gz0; w[3] = gx0*gy1*gz1;
        w[4] = gx1*gy0*gz0; w[5] = gx1*gy0*gz1; w[6] = gx1*gy1*gz0; w[7] = gx1*gy1*gz1;

        float sigma = 0, c0 = 0, c1 = 0, c2 = 0;
        #pragma unroll
        for (int c = 0; c < 8; c++) {
            sigma += w[c] * csig[c];
            c0    += w[c] * cr0[c];
            c1    += w[c] * cr1[c];
            c2    += w[c] * cr2[c];
        }

        const float la = -STEPSZ * fmaxf(sigma, 0.0f) * ds;
        const float e  = __expf(la);
        const float ws = light * (1.0f - e);
        c0 = fmaxf(c0 + 0.5f, 0.0f);
        c1 = fmaxf(c1 + 0.5f, 0.0f);
        c2 = fmaxf(c2 + 0.5f, 0.0f);

        aR += ws * c0; aG += ws * c1; aB += ws * c2;
        aA += ws;
        const float dd = t * ds;
        aD1 += ws * dd;
        aD2 += ws * dd * dd;
        light *= e;
        ll    += la;
    }

    // ---- wave-level segment stitch (associative transmittance combine) ----
    // inclusive prefix scan of ll over lanes (lane order == segment order)
    float inc = ll;
    #pragma unroll
    for (int off = 1; off < 64; off <<= 1) {
        const float v = __shfl_up(inc, off, 64);
        if (lane >= off) inc += v;
    }
    const float pre = inc - ll;          // exclusive prefix
    const float T   = __expf(pre);
    aR *= T; aG *= T; aB *= T; aA *= T; aD1 *= T; aD2 *= T;

    #pragma unroll
    for (int off = 32; off; off >>= 1) {
        aR  += __shfl_xor(aR,  off, 64);
        aG  += __shfl_xor(aG,  off, 64);
        aB  += __shfl_xor(aB,  off, 64);
        aA  += __shfl_xor(aA,  off, 64);
        aD1 += __shfl_xor(aD1, off, 64);
        aD2 += __shfl_xor(aD2, off, 64);
    }
    const float llt = __shfl(inc, 63, 64);   // total log transmittance

    if (lane == 0) {
        const float bg    = __expf(llt);
        const float denom = fmaxf(aA, 1e-10f);
        const float E     = aD1 / denom;
        const float ov    = aD2 - 2.0f * E * aD1 + E * E * aA;

        const int o = ray * 6;
        out[o + 0] = aR + bg;
        out[o + 1] = aG + bg;
        out[o + 2] = aB + bg;
        out[o + 3] = aA;
        out[o + 4] = E;
        out[o + 5] = ov / denom;
    }
}

extern "C" void kernel_launch(void* const* d_in, const int* in_sizes, int n_in,
                              void* d_out, int out_size, void* d_ws, size_t ws_size,
                              hipStream_t stream) {
    const float* origins = (const float*)d_in[0];
    const float* dirs    = (const float*)d_in[1];
    const int*   links   = (const int*)d_in[2];
    const float* density = (const float*)d_in[3];
    const float* sh      = (const float*)d_in[4];
    float* out = (float*)d_out;

    dim3 mgrid(NRAYS / RPB);   // 4096 blocks
    dim3 mblock(TPB);          // 256 threads = 4 rays x 64 segments

    if (ws_size >= PACK_BYTES) {
        _Float16* pack = (_Float16*)d_ws;
        repack_kernel<<<dim3(NVOX / 256), dim3(256), 0, stream>>>(links, density, sh, pack);
        march_kernel<true><<<mgrid, mblock, 0, stream>>>(
            origins, dirs, links, density, sh, pack, out);
    } else {
        march_kernel<false><<<mgrid, mblock, 0, stream>>>(
            origins, dirs, links, density, sh, (const _Float16*)nullptr, out);
    }
}

// Round 2
// 679.589 us; speedup vs baseline: 1.1135x; 1.1135x over previous
//
#include <hip/hip_runtime.h>
#include <math.h>

#define GRIDN    128
#define NRAYS    16384
#define STEPSZ   0.5f
#define MAXSTEPS 320
#define NVOX     (GRIDN * GRIDN * GRIDN)
// fp16 record: 32 halves (64 B) per VOXEL: [0]=density, [1..27]=sh, pad.
// Voxel-indexed (links folded in at repack time); empty voxels = zero record.
#define PACK_BYTES ((size_t)(NVOX + 1) * 64)

// ---- tile/segment decomposition for the march ----
#define TILES  256                  // 16x16 tiles of 8x8 pixels
#define NSEG   16                   // segments per ray (separate waves)
#define SPSEG  (MAXSTEPS / NSEG)    // 20 steps per segment
#define WPB    4                    // waves per block
#define PART_FLOATS ((size_t)NSEG * TILES * 64 * 8)
#define PART_BYTES  (PART_FLOATS * 4)

typedef _Float16 half8 __attribute__((ext_vector_type(8)));

// ---------------------------------------------------------------------------
// Prologue: voxel-indexed repack (unchanged from round 1 — correct & cheap).
// ---------------------------------------------------------------------------
__global__ __launch_bounds__(256, 5)
void repack_kernel(const int*   __restrict__ links,
                   const float* __restrict__ density,
                   const float* __restrict__ sh,
                   _Float16*    __restrict__ pack)
{
    __shared__ float buf[4][64 * 27];
    const int lane  = threadIdx.x & 63;
    const int wv    = threadIdx.x >> 6;
    const int vbase = (blockIdx.x * 4 + wv) * 64;

    const float* src = sh + (size_t)vbase * 27;
    float* b = buf[wv];
    #pragma unroll
    for (int j = 0; j < 27; j++)
        b[j * 64 + lane] = src[j * 64 + lane];

    const int v   = vbase + lane;
    const int lnk = links[v];
    float dens = 0.0f;
    if (lnk >= 0) dens = density[lnk];
    __syncthreads();

    __align__(16) _Float16 rec[32];
    #pragma unroll
    for (int k = 0; k < 32; k++) rec[k] = (_Float16)0.0f;

    if (lnk >= 0) {
        rec[0] = (_Float16)dens;
        if (lnk >= vbase && lnk < vbase + 64) {
            const float* myrow = b + (lnk - vbase) * 27;
            #pragma unroll
            for (int k = 0; k < 27; k++) rec[1 + k] = (_Float16)myrow[k];
        } else {
            const float* row = sh + (size_t)lnk * 27;
            #pragma unroll
            for (int k = 0; k < 27; k++) rec[1 + k] = (_Float16)row[k];
        }
    }

    uint4* dst = (uint4*)(pack + (size_t)v * 32);
    const uint4* rp = (const uint4*)rec;
    dst[0] = rp[0]; dst[1] = rp[1]; dst[2] = rp[2]; dst[3] = rp[3];
}

// ---------------------------------------------------------------------------
// March partials: one wave = 64 adjacent rays (8x8 pixel tile) at ONE segment
// (SPSEG steps). Lanes march in lockstep through the same neighborhood, so
// the 8-corner gathers overlap heavily across lanes (cache-coherent).
// Each lane is an independent ray-segment: no cross-lane ops, no LDS.
// Writes an 8-float partial per (ray, seg): [R,G,B,A,D1,D2,ll,pad].
// ---------------------------------------------------------------------------
__global__ __launch_bounds__(256, 8)
void march_part_kernel(const float* __restrict__ origins,
                       const float* __restrict__ dirs,
                       const _Float16* __restrict__ pack,
                       float* __restrict__ parts)
{
    const int lane = threadIdx.x & 63;
    const int gw   = blockIdx.x * WPB + (threadIdx.x >> 6);
    const int seg  = gw >> 8;              // gw / TILES  (seg-major: adjacent
    const int tile = gw & (TILES - 1);     //  blocks share a depth region)
    const int ray  = (((tile >> 4) * 8 + (lane >> 3)) << 7)
                   + ((tile & 15) << 3) + (lane & 7);

    // ---- ray setup ----
    const float owx = origins[ray * 3 + 0];
    const float owy = origins[ray * 3 + 1];
    const float owz = origins[ray * 3 + 2];
    const float dwx = dirs[ray * 3 + 0];
    const float dwy = dirs[ray * 3 + 1];
    const float dwz = dirs[ray * 3 + 2];

    const float invn = 1.0f / sqrtf(dwx * dwx + dwy * dwy + dwz * dwz);
    const float vx = dwx * invn, vy = dwy * invn, vz = dwz * invn;

    const float ox = 63.5f + owx * 64.0f;
    const float oy = 63.5f + owy * 64.0f;
    const float oz = 63.5f + owz * 64.0f;

    const float sxx = vx * 64.0f, syy = vy * 64.0f, szz = vz * 64.0f;
    const float ds  = 1.0f / sqrtf(sxx * sxx + syy * syy + szz * szz);
    const float dx = sxx * ds, dy = syy * ds, dz = szz * ds;

    float shm[9];
    shm[0] = 0.28209479177387814f;
    shm[1] = -0.4886025119029199f * vy;
    shm[2] =  0.4886025119029199f * vz;
    shm[3] = -0.4886025119029199f * vx;
    shm[4] =  1.0925484305920792f * vx * vy;
    shm[5] = -1.0925484305920792f * vy * vz;
    shm[6] =  0.31539156525252005f * (2.0f * vz * vz - vx * vx - vy * vy);
    shm[7] = -1.0925484305920792f * vx * vz;
    shm[8] =  0.5462742152960396f * (vx * vx - vy * vy);

    float t0 = 0.0f, tmax = 1e9f;
    {
        const float o3[3] = { ox, oy, oz };
        const float d3[3] = { dx, dy, dz };
        #pragma unroll
        for (int a = 0; a < 3; a++) {
            if (d3[a] != 0.0f) {
                float inv = 1.0f / d3[a];
                float ta = (-0.5f  - o3[a]) * inv;
                float tb = (127.5f - o3[a]) * inv;
                t0   = fmaxf(t0,   fminf(ta, tb));
                tmax = fminf(tmax, fmaxf(ta, tb));
            }
        }
    }

    float ll = 0.0f;
    float light = 1.0f;
    float aR = 0, aG = 0, aB = 0, aA = 0, aD1 = 0, aD2 = 0;

    int cached_cell = -1;
    float csig[8], cr0[8], cr1[8], cr2[8];

    const int k0 = seg * SPSEG;
    for (int i = 0; i < SPSEG; i++) {
        const float t = t0 + (float)(k0 + i) * STEPSZ;
        if (t > tmax) break;

        float px = fminf(fmaxf(ox + t * dx, 0.0f), 127.0f);
        float py = fminf(fmaxf(oy + t * dy, 0.0f), 127.0f);
        float pz = fminf(fmaxf(oz + t * dz, 0.0f), 127.0f);
        const int lx = min(max((int)px, 0), 126);
        const int ly = min(max((int)py, 0), 126);
        const int lz = min(max((int)pz, 0), 126);
        const float fx = px - (float)lx;
        const float fy = py - (float)ly;
        const float fz = pz - (float)lz;

        const int cell = (lx << 14) | (ly << 7) | lz;
        if (cell != cached_cell) {
            cached_cell = cell;
            #pragma unroll
            for (int c = 0; c < 8; c++) {
                const int cdx = (c >> 2) & 1, cdy = (c >> 1) & 1, cdz = c & 1;
                const int vox = cell + (cdx << 14) + (cdy << 7) + cdz;
                const half8* pr = (const half8*)(pack + (size_t)vox * 32);
                const half8 h0 = pr[0], h1 = pr[1], h2 = pr[2], h3 = pr[3];
                csig[c] = (float)h0[0];
                cr0[c] = shm[0]*(float)h0[1] + shm[1]*(float)h0[2] + shm[2]*(float)h0[3]
                       + shm[3]*(float)h0[4] + shm[4]*(float)h0[5] + shm[5]*(float)h0[6]
                       + shm[6]*(float)h0[7] + shm[7]*(float)h1[0] + shm[8]*(float)h1[1];
                cr1[c] = shm[0]*(float)h1[2] + shm[1]*(float)h1[3] + shm[2]*(float)h1[4]
                       + shm[3]*(float)h1[5] + shm[4]*(float)h1[6] + shm[5]*(float)h1[7]
                       + shm[6]*(float)h2[0] + shm[7]*(float)h2[1] + shm[8]*(float)h2[2];
                cr2[c] = shm[0]*(float)h2[3] + shm[1]*(float)h2[4] + shm[2]*(float)h2[5]
                       + shm[3]*(float)h2[6] + shm[4]*(float)h2[7] + shm[5]*(float)h3[0]
                       + shm[6]*(float)h3[1] + shm[7]*(float)h3[2] + shm[8]*(float)h3[3];
            }
        }

        const float gx1 = fx, gx0 = 1.0f - fx;
        const float gy1 = fy, gy0 = 1.0f - fy;
        const float gz1 = fz, gz0 = 1.0f - fz;
        float w[8];
        w[0] = gx0*gy0*gz0; w[1] = gx0*gy0*gz1; w[2] = gx0*gy1*gz0; w[3] = gx0*gy1*gz1;
        w[4] = gx1*gy0*gz0; w[5] = gx1*gy0*gz1; w[6] = gx1*gy1*gz0; w[7] = gx1*gy1*gz1;

        float sigma = 0, c0 = 0, c1 = 0, c2 = 0;
        #pragma unroll
        for (int c = 0; c < 8; c++) {
            sigma += w[c] * csig[c];
            c0    += w[c] * cr0[c];
            c1    += w[c] * cr1[c];
            c2    += w[c] * cr2[c];
        }

        const float la = -STEPSZ * fmaxf(sigma, 0.0f) * ds;
        const float e  = __expf(la);
        const float ws = light * (1.0f - e);
        c0 = fmaxf(c0 + 0.5f, 0.0f);
        c1 = fmaxf(c1 + 0.5f, 0.0f);
        c2 = fmaxf(c2 + 0.5f, 0.0f);

        aR += ws * c0; aG += ws * c1; aB += ws * c2;
        aA += ws;
        const float dd = t * ds;
        aD1 += ws * dd;
        aD2 += ws * dd * dd;
        light *= e;
        ll    += la;
    }

    float4* prt = (float4*)(parts + ((size_t)(seg * TILES + tile) * 64 + lane) * 8);
    prt[0] = make_float4(aR, aG, aB, aA);
    prt[1] = make_float4(aD1, aD2, ll, 0.0f);
}

// ---------------------------------------------------------------------------
// Stitch: one thread per ray combines its NSEG partials (associative
// transmittance decomposition, same math as the verified LDS/shfl stitches).
// ---------------------------------------------------------------------------
__global__ __launch_bounds__(256)
void stitch_kernel(const float* __restrict__ parts, float* __restrict__ out)
{
    const int idx  = blockIdx.x * 256 + threadIdx.x;   // (tile, lane) id
    const int tile = idx >> 6;
    const int lane = idx & 63;
    const int ray  = (((tile >> 4) * 8 + (lane >> 3)) << 7)
                   + ((tile & 15) << 3) + (lane & 7);

    float pre = 0.0f;
    float R = 0, G = 0, B = 0, A = 0, D1 = 0, D2 = 0;
    #pragma unroll 4
    for (int s = 0; s < NSEG; s++) {
        const float4* p = (const float4*)(parts + ((size_t)(s * TILES + tile) * 64 + lane) * 8);
        const float4 a = p[0];
        const float4 b = p[1];
        const float T = __expf(pre);
        R  += T * a.x;  G  += T * a.y;  B  += T * a.z;  A += T * a.w;
        D1 += T * b.x;  D2 += T * b.y;
        pre += b.z;
    }

    const float bg    = __expf(pre);
    const float denom = fmaxf(A, 1e-10f);
    const float E     = D1 / denom;
    const float ov    = D2 - 2.0f * E * D1 + E * E * A;

    const int o = ray * 6;
    out[o + 0] = R + bg;
    out[o + 1] = G + bg;
    out[o + 2] = B + bg;
    out[o + 3] = A;
    out[o + 4] = E;
    out[o + 5] = ov / denom;
}

// ---------------------------------------------------------------------------
// Fallback (no workspace): round-1 verified math, direct links/density/sh
// reads, wave = 1 ray with shfl stitch. Rarely used; correctness-first.
// ---------------------------------------------------------------------------
__global__ __launch_bounds__(256, 8)
void march_fallback_kernel(const float* __restrict__ origins,
                           const float* __restrict__ dirs,
                           const int*   __restrict__ links,
                           const float* __restrict__ density,
                           const float* __restrict__ sh,
                           float* __restrict__ out)
{
    const int tid  = threadIdx.x;
    const int lane = tid & 63;
    const int r    = tid >> 6;
    const int ray  = blockIdx.x * 4 + r;

    const float owx = origins[ray * 3 + 0];
    const float owy = origins[ray * 3 + 1];
    const float owz = origins[ray * 3 + 2];
    const float dwx = dirs[ray * 3 + 0];
    const float dwy = dirs[ray * 3 + 1];
    const float dwz = dirs[ray * 3 + 2];

    const float invn = 1.0f / sqrtf(dwx * dwx + dwy * dwy + dwz * dwz);
    const float vx = dwx * invn, vy = dwy * invn, vz = dwz * invn;
    const float ox = 63.5f + owx * 64.0f;
    const float oy = 63.5f + owy * 64.0f;
    const float oz = 63.5f + owz * 64.0f;
    const float sxx = vx * 64.0f, syy = vy * 64.0f, szz = vz * 64.0f;
    const float ds  = 1.0f / sqrtf(sxx * sxx + syy * syy + szz * szz);
    const float dx = sxx * ds, dy = syy * ds, dz = szz * ds;

    float shm[9];
    shm[0] = 0.28209479177387814f;
    shm[1] = -0.4886025119029199f * vy;
    shm[2] =  0.4886025119029199f * vz;
    shm[3] = -0.4886025119029199f * vx;
    shm[4] =  1.0925484305920792f * vx * vy;
    shm[5] = -1.0925484305920792f * vy * vz;
    shm[6] =  0.31539156525252005f * (2.0f * vz * vz - vx * vx - vy * vy);
    shm[7] = -1.0925484305920792f * vx * vz;
    shm[8] =  0.5462742152960396f * (vx * vx - vy * vy);

    float t0 = 0.0f, tmax = 1e9f;
    {
        const float o3[3] = { ox, oy, oz };
        const float d3[3] = { dx, dy, dz };
        #pragma unroll
        for (int a = 0; a < 3; a++) {
            if (d3[a] != 0.0f) {
                float inv = 1.0f / d3[a];
                float ta = (-0.5f  - o3[a]) * inv;
                float tb = (127.5f - o3[a]) * inv;
                t0   = fmaxf(t0,   fminf(ta, tb));
                tmax = fminf(tmax, fmaxf(ta, tb));
            }
        }
    }

    float ll = 0.0f, light = 1.0f;
    float aR = 0, aG = 0, aB = 0, aA = 0, aD1 = 0, aD2 = 0;
    int cached_cell = -1;
    float csig[8], cr0[8], cr1[8], cr2[8];

    const int k0 = lane * (MAXSTEPS / 64);
    for (int i = 0; i < MAXSTEPS / 64; i++) {
        const float t = t0 + (float)(k0 + i) * STEPSZ;
        if (t > tmax) break;

        float px = fminf(fmaxf(ox + t * dx, 0.0f), 127.0f);
        float py = fminf(fmaxf(oy + t * dy, 0.0f), 127.0f);
        float pz = fminf(fmaxf(oz + t * dz, 0.0f), 127.0f);
        const int lx = min(max((int)px, 0), 126);
        const int ly = min(max((int)py, 0), 126);
        const int lz = min(max((int)pz, 0), 126);
        const float fx = px - (float)lx;
        const float fy = py - (float)ly;
        const float fz = pz - (float)lz;

        const int cell = (lx << 14) | (ly << 7) | lz;
        if (cell != cached_cell) {
            cached_cell = cell;
            #pragma unroll
            for (int c = 0; c < 8; c++) {
                const int cdx = (c >> 2) & 1, cdy = (c >> 1) & 1, cdz = c & 1;
                const int idx = cell + (cdx << 14) + (cdy << 7) + cdz;
                const int lnk = links[idx];
                float sg = 0, q0 = 0, q1 = 0, q2 = 0;
                if (lnk >= 0) {
                    sg = density[lnk];
                    const float* row = sh + (size_t)lnk * 27;
                    #pragma unroll
                    for (int k = 0; k < 9; k++) {
                        const float m = shm[k];
                        q0 += m * row[k];
                        q1 += m * row[9 + k];
                        q2 += m * row[18 + k];
                    }
                }
                csig[c] = sg; cr0[c] = q0; cr1[c] = q1; cr2[c] = q2;
            }
        }

        const float gx1 = fx, gx0 = 1.0f - fx;
        const float gy1 = fy, gy0 = 1.0f - fy;
        const float gz1 = fz, gz0 = 1.0f - fz;
        float w[8];
        w[0] = gx0*gy0*gz0; w[1] = gx0*gy0*gz1; w[2] = gx0*gy1*gz0; w[3] = gx0*gy1*gz1;
        w[4] = gx1*gy0*gz0; w[5] = gx1*gy0*gz1; w[6] = gx1*gy1*gz0; w[7] = gx1*gy1*gz1;

        float sigma = 0, c0 = 0, c1 = 0, c2 = 0;
        #pragma unroll
        for (int c = 0; c < 8; c++) {
            sigma += w[c] * csig[c];
            c0    += w[c] * cr0[c];
            c1    += w[c] * cr1[c];
            c2    += w[c] * cr2[c];
        }

        const float la = -STEPSZ * fmaxf(sigma, 0.0f) * ds;
        const float e  = __expf(la);
        const float ws = light * (1.0f - e);
        c0 = fmaxf(c0 + 0.5f, 0.0f);
        c1 = fmaxf(c1 + 0.5f, 0.0f);
        c2 = fmaxf(c2 + 0.5f, 0.0f);

        aR += ws * c0; aG += ws * c1; aB += ws * c2;
        aA += ws;
        const float dd = t * ds;
        aD1 += ws * dd;
        aD2 += ws * dd * dd;
        light *= e;
        ll    += la;
    }

    float inc = ll;
    #pragma unroll
    for (int off = 1; off < 64; off <<= 1) {
        const float v = __shfl_up(inc, off, 64);
        if (lane >= off) inc += v;
    }
    const float pre = inc - ll;
    const float T   = __expf(pre);
    aR *= T; aG *= T; aB *= T; aA *= T; aD1 *= T; aD2 *= T;

    #pragma unroll
    for (int off = 32; off; off >>= 1) {
        aR  += __shfl_xor(aR,  off, 64);
        aG  += __shfl_xor(aG,  off, 64);
        aB  += __shfl_xor(aB,  off, 64);
        aA  += __shfl_xor(aA,  off, 64);
        aD1 += __shfl_xor(aD1, off, 64);
        aD2 += __shfl_xor(aD2, off, 64);
    }
    const float llt = __shfl(inc, 63, 64);

    if (lane == 0) {
        const float bg    = __expf(llt);
        const float denom = fmaxf(aA, 1e-10f);
        const float E     = aD1 / denom;
        const float ov    = aD2 - 2.0f * E * aD1 + E * E * aA;
        const int o = ray * 6;
        out[o + 0] = aR + bg;
        out[o + 1] = aG + bg;
        out[o + 2] = aB + bg;
        out[o + 3] = aA;
        out[o + 4] = E;
        out[o + 5] = ov / denom;
    }
}

extern "C" void kernel_launch(void* const* d_in, const int* in_sizes, int n_in,
                              void* d_out, int out_size, void* d_ws, size_t ws_size,
                              hipStream_t stream) {
    const float* origins = (const float*)d_in[0];
    const float* dirs    = (const float*)d_in[1];
    const int*   links   = (const int*)d_in[2];
    const float* density = (const float*)d_in[3];
    const float* sh      = (const float*)d_in[4];
    float* out = (float*)d_out;

    if (ws_size >= PACK_BYTES + PART_BYTES) {
        _Float16* pack  = (_Float16*)d_ws;
        float*    parts = (float*)((char*)d_ws + PACK_BYTES);
        repack_kernel<<<dim3(NVOX / 256), dim3(256), 0, stream>>>(links, density, sh, pack);
        march_part_kernel<<<dim3(TILES * NSEG / WPB), dim3(256), 0, stream>>>(
            origins, dirs, pack, parts);
        stitch_kernel<<<dim3(NRAYS / 256), dim3(256), 0, stream>>>(parts, out);
    } else {
        march_fallback_kernel<<<dim3(NRAYS / 4), dim3(256), 0, stream>>>(
            origins, dirs, links, density, sh, out);
    }
}

// Round 3
// 668.465 us; speedup vs baseline: 1.1320x; 1.0166x over previous
//
#include <hip/hip_runtime.h>
#include <math.h>

#define GRIDN    128
#define NRAYS    16384
#define STEPSZ   0.5f
#define MAXSTEPS 320
#define NVOX     (GRIDN * GRIDN * GRIDN)
// fp16 record: 32 halves (64 B) per VOXEL: [0]=density, [1..27]=sh, pad.
// Voxel-indexed (links folded in at repack time); empty voxels = zero record.
#define PACK_BYTES ((size_t)(NVOX + 1) * 64)

// ---- tile/segment decomposition for the march ----
#define TILES  256                  // 16x16 tiles of 8x8 pixels
#define WPB    4                    // waves per block

static inline size_t part_bytes(int nseg) {
    return (size_t)nseg * TILES * 64 * 8 * 4;
}

typedef _Float16 half8 __attribute__((ext_vector_type(8)));

// ---------------------------------------------------------------------------
// Prologue: voxel-indexed repack. fp16 LDS staging (13.8 KB/block -> 8
// blocks/CU vs 5 for fp32) — conversion happens during the coalesced load.
// Stride-27 half reads are ~2-way bank aliased = free.
// ---------------------------------------------------------------------------
__global__ __launch_bounds__(256, 6)
void repack_kernel(const int*   __restrict__ links,
                   const float* __restrict__ density,
                   const float* __restrict__ sh,
                   _Float16*    __restrict__ pack)
{
    __shared__ _Float16 buf[4][64 * 27];   // 13824 B/block
    const int lane  = threadIdx.x & 63;
    const int wv    = threadIdx.x >> 6;
    const int vbase = (blockIdx.x * 4 + wv) * 64;

    const float* src = sh + (size_t)vbase * 27;
    _Float16* b = buf[wv];
    #pragma unroll
    for (int j = 0; j < 27; j++)
        b[j * 64 + lane] = (_Float16)src[j * 64 + lane];   // coalesced, cvt inline

    const int v   = vbase + lane;
    const int lnk = links[v];
    float dens = 0.0f;
    if (lnk >= 0) dens = density[lnk];
    __syncthreads();

    __align__(16) _Float16 rec[32];
    #pragma unroll
    for (int k = 0; k < 32; k++) rec[k] = (_Float16)0.0f;

    if (lnk >= 0) {
        rec[0] = (_Float16)dens;
        if (lnk >= vbase && lnk < vbase + 64) {
            const _Float16* myrow = b + (lnk - vbase) * 27;
            #pragma unroll
            for (int k = 0; k < 27; k++) rec[1 + k] = myrow[k];
        } else {
            const float* row = sh + (size_t)lnk * 27;     // rare general-case gather
            #pragma unroll
            for (int k = 0; k < 27; k++) rec[1 + k] = (_Float16)row[k];
        }
    }

    uint4* dst = (uint4*)(pack + (size_t)v * 32);
    const uint4* rp = (const uint4*)rec;
    dst[0] = rp[0]; dst[1] = rp[1]; dst[2] = rp[2]; dst[3] = rp[3];
}

// ---------------------------------------------------------------------------
// March partials: one wave = 64 adjacent rays (8x8 pixel tile) at ONE segment.
// NSEG=32 -> 8192 waves = full 32 waves/CU residency.
// Writes an 8-float partial per (ray, seg): [R,G,B,A,D1,D2,ll,pad].
// ---------------------------------------------------------------------------
template <int NSEG>
__global__ __launch_bounds__(256, 8)
void march_part_kernel(const float* __restrict__ origins,
                       const float* __restrict__ dirs,
                       const _Float16* __restrict__ pack,
                       float* __restrict__ parts)
{
    constexpr int SPSEG = MAXSTEPS / NSEG;
    const int lane = threadIdx.x & 63;
    const int gw   = blockIdx.x * WPB + (threadIdx.x >> 6);
    const int seg  = gw >> 8;              // gw / TILES  (seg-major)
    const int tile = gw & (TILES - 1);
    const int ray  = (((tile >> 4) * 8 + (lane >> 3)) << 7)
                   + ((tile & 15) << 3) + (lane & 7);

    // ---- ray setup ----
    const float owx = origins[ray * 3 + 0];
    const float owy = origins[ray * 3 + 1];
    const float owz = origins[ray * 3 + 2];
    const float dwx = dirs[ray * 3 + 0];
    const float dwy = dirs[ray * 3 + 1];
    const float dwz = dirs[ray * 3 + 2];

    const float invn = 1.0f / sqrtf(dwx * dwx + dwy * dwy + dwz * dwz);
    const float vx = dwx * invn, vy = dwy * invn, vz = dwz * invn;

    const float ox = 63.5f + owx * 64.0f;
    const float oy = 63.5f + owy * 64.0f;
    const float oz = 63.5f + owz * 64.0f;

    const float sxx = vx * 64.0f, syy = vy * 64.0f, szz = vz * 64.0f;
    const float ds  = 1.0f / sqrtf(sxx * sxx + syy * syy + szz * szz);
    const float dx = sxx * ds, dy = syy * ds, dz = szz * ds;

    float shm[9];
    shm[0] = 0.28209479177387814f;
    shm[1] = -0.4886025119029199f * vy;
    shm[2] =  0.4886025119029199f * vz;
    shm[3] = -0.4886025119029199f * vx;
    shm[4] =  1.0925484305920792f * vx * vy;
    shm[5] = -1.0925484305920792f * vy * vz;
    shm[6] =  0.31539156525252005f * (2.0f * vz * vz - vx * vx - vy * vy);
    shm[7] = -1.0925484305920792f * vx * vz;
    shm[8] =  0.5462742152960396f * (vx * vx - vy * vy);

    float t0 = 0.0f, tmax = 1e9f;
    {
        const float o3[3] = { ox, oy, oz };
        const float d3[3] = { dx, dy, dz };
        #pragma unroll
        for (int a = 0; a < 3; a++) {
            if (d3[a] != 0.0f) {
                float inv = 1.0f / d3[a];
                float ta = (-0.5f  - o3[a]) * inv;
                float tb = (127.5f - o3[a]) * inv;
                t0   = fmaxf(t0,   fminf(ta, tb));
                tmax = fminf(tmax, fmaxf(ta, tb));
            }
        }
    }

    float ll = 0.0f;
    float light = 1.0f;
    float aR = 0, aG = 0, aB = 0, aA = 0, aD1 = 0, aD2 = 0;

    int cached_cell = -1;
    float csig[8], cr0[8], cr1[8], cr2[8];

    const int k0 = seg * SPSEG;
    for (int i = 0; i < SPSEG; i++) {
        const float t = t0 + (float)(k0 + i) * STEPSZ;
        if (t > tmax) break;

        float px = fminf(fmaxf(ox + t * dx, 0.0f), 127.0f);
        float py = fminf(fmaxf(oy + t * dy, 0.0f), 127.0f);
        float pz = fminf(fmaxf(oz + t * dz, 0.0f), 127.0f);
        const int lx = min(max((int)px, 0), 126);
        const int ly = min(max((int)py, 0), 126);
        const int lz = min(max((int)pz, 0), 126);
        const float fx = px - (float)lx;
        const float fy = py - (float)ly;
        const float fz = pz - (float)lz;

        const int cell = (lx << 14) | (ly << 7) | lz;
        if (cell != cached_cell) {
            cached_cell = cell;
            #pragma unroll
            for (int c = 0; c < 8; c++) {
                const int cdx = (c >> 2) & 1, cdy = (c >> 1) & 1, cdz = c & 1;
                const int vox = cell + (cdx << 14) + (cdy << 7) + cdz;
                const half8* pr = (const half8*)(pack + (size_t)vox * 32);
                const half8 h0 = pr[0], h1 = pr[1], h2 = pr[2], h3 = pr[3];
                csig[c] = (float)h0[0];
                cr0[c] = shm[0]*(float)h0[1] + shm[1]*(float)h0[2] + shm[2]*(float)h0[3]
                       + shm[3]*(float)h0[4] + shm[4]*(float)h0[5] + shm[5]*(float)h0[6]
                       + shm[6]*(float)h0[7] + shm[7]*(float)h1[0] + shm[8]*(float)h1[1];
                cr1[c] = shm[0]*(float)h1[2] + shm[1]*(float)h1[3] + shm[2]*(float)h1[4]
                       + shm[3]*(float)h1[5] + shm[4]*(float)h1[6] + shm[5]*(float)h1[7]
                       + shm[6]*(float)h2[0] + shm[7]*(float)h2[1] + shm[8]*(float)h2[2];
                cr2[c] = shm[0]*(float)h2[3] + shm[1]*(float)h2[4] + shm[2]*(float)h2[5]
                       + shm[3]*(float)h2[6] + shm[4]*(float)h2[7] + shm[5]*(float)h3[0]
                       + shm[6]*(float)h3[1] + shm[7]*(float)h3[2] + shm[8]*(float)h3[3];
            }
        }

        const float gx1 = fx, gx0 = 1.0f - fx;
        const float gy1 = fy, gy0 = 1.0f - fy;
        const float gz1 = fz, gz0 = 1.0f - fz;
        float w[8];
        w[0] = gx0*gy0*gz0; w[1] = gx0*gy0*gz1; w[2] = gx0*gy1*gz0; w[3] = gx0*gy1*gz1;
        w[4] = gx1*gy0*gz0; w[5] = gx1*gy0*gz1; w[6] = gx1*gy1*gz0; w[7] = gx1*gy1*gz1;

        float sigma = 0, c0 = 0, c1 = 0, c2 = 0;
        #pragma unroll
        for (int c = 0; c < 8; c++) {
            sigma += w[c] * csig[c];
            c0    += w[c] * cr0[c];
            c1    += w[c] * cr1[c];
            c2    += w[c] * cr2[c];
        }

        const float la = -STEPSZ * fmaxf(sigma, 0.0f) * ds;
        const float e  = __expf(la);
        const float ws = light * (1.0f - e);
        c0 = fmaxf(c0 + 0.5f, 0.0f);
        c1 = fmaxf(c1 + 0.5f, 0.0f);
        c2 = fmaxf(c2 + 0.5f, 0.0f);

        aR += ws * c0; aG += ws * c1; aB += ws * c2;
        aA += ws;
        const float dd = t * ds;
        aD1 += ws * dd;
        aD2 += ws * dd * dd;
        light *= e;
        ll    += la;
    }

    float4* prt = (float4*)(parts + ((size_t)(seg * TILES + tile) * 64 + lane) * 8);
    prt[0] = make_float4(aR, aG, aB, aA);
    prt[1] = make_float4(aD1, aD2, ll, 0.0f);
}

// ---------------------------------------------------------------------------
// Stitch: one thread per ray combines its NSEG partials.
// ---------------------------------------------------------------------------
template <int NSEG>
__global__ __launch_bounds__(256)
void stitch_kernel(const float* __restrict__ parts, float* __restrict__ out)
{
    const int idx  = blockIdx.x * 256 + threadIdx.x;   // (tile, lane) id
    const int tile = idx >> 6;
    const int lane = idx & 63;
    const int ray  = (((tile >> 4) * 8 + (lane >> 3)) << 7)
                   + ((tile & 15) << 3) + (lane & 7);

    float pre = 0.0f;
    float R = 0, G = 0, B = 0, A = 0, D1 = 0, D2 = 0;
    #pragma unroll 4
    for (int s = 0; s < NSEG; s++) {
        const float4* p = (const float4*)(parts + ((size_t)(s * TILES + tile) * 64 + lane) * 8);
        const float4 a = p[0];
        const float4 b = p[1];
        const float T = __expf(pre);
        R  += T * a.x;  G  += T * a.y;  B  += T * a.z;  A += T * a.w;
        D1 += T * b.x;  D2 += T * b.y;
        pre += b.z;
    }

    const float bg    = __expf(pre);
    const float denom = fmaxf(A, 1e-10f);
    const float E     = D1 / denom;
    const float ov    = D2 - 2.0f * E * D1 + E * E * A;

    const int o = ray * 6;
    out[o + 0] = R + bg;
    out[o + 1] = G + bg;
    out[o + 2] = B + bg;
    out[o + 3] = A;
    out[o + 4] = E;
    out[o + 5] = ov / denom;
}

// ---------------------------------------------------------------------------
// Fallback (no workspace): verified round-1 math, direct links/density/sh
// reads, wave = 1 ray with shfl stitch.
// ---------------------------------------------------------------------------
__global__ __launch_bounds__(256, 8)
void march_fallback_kernel(const float* __restrict__ origins,
                           const float* __restrict__ dirs,
                           const int*   __restrict__ links,
                           const float* __restrict__ density,
                           const float* __restrict__ sh,
                           float* __restrict__ out)
{
    const int tid  = threadIdx.x;
    const int lane = tid & 63;
    const int r    = tid >> 6;
    const int ray  = blockIdx.x * 4 + r;

    const float owx = origins[ray * 3 + 0];
    const float owy = origins[ray * 3 + 1];
    const float owz = origins[ray * 3 + 2];
    const float dwx = dirs[ray * 3 + 0];
    const float dwy = dirs[ray * 3 + 1];
    const float dwz = dirs[ray * 3 + 2];

    const float invn = 1.0f / sqrtf(dwx * dwx + dwy * dwy + dwz * dwz);
    const float vx = dwx * invn, vy = dwy * invn, vz = dwz * invn;
    const float ox = 63.5f + owx * 64.0f;
    const float oy = 63.5f + owy * 64.0f;
    const float oz = 63.5f + owz * 64.0f;
    const float sxx = vx * 64.0f, syy = vy * 64.0f, szz = vz * 64.0f;
    const float ds  = 1.0f / sqrtf(sxx * sxx + syy * syy + szz * szz);
    const float dx = sxx * ds, dy = syy * ds, dz = szz * ds;

    float shm[9];
    shm[0] = 0.28209479177387814f;
    shm[1] = -0.4886025119029199f * vy;
    shm[2] =  0.4886025119029199f * vz;
    shm[3] = -0.4886025119029199f * vx;
    shm[4] =  1.0925484305920792f * vx * vy;
    shm[5] = -1.0925484305920792f * vy * vz;
    shm[6] =  0.31539156525252005f * (2.0f * vz * vz - vx * vx - vy * vy);
    shm[7] = -1.0925484305920792f * vx * vz;
    shm[8] =  0.5462742152960396f * (vx * vx - vy * vy);

    float t0 = 0.0f, tmax = 1e9f;
    {
        const float o3[3] = { ox, oy, oz };
        const float d3[3] = { dx, dy, dz };
        #pragma unroll
        for (int a = 0; a < 3; a++) {
            if (d3[a] != 0.0f) {
                float inv = 1.0f / d3[a];
                float ta = (-0.5f  - o3[a]) * inv;
                float tb = (127.5f - o3[a]) * inv;
                t0   = fmaxf(t0,   fminf(ta, tb));
                tmax = fminf(tmax, fmaxf(ta, tb));
            }
        }
    }

    float ll = 0.0f, light = 1.0f;
    float aR = 0, aG = 0, aB = 0, aA = 0, aD1 = 0, aD2 = 0;
    int cached_cell = -1;
    float csig[8], cr0[8], cr1[8], cr2[8];

    const int k0 = lane * (MAXSTEPS / 64);
    for (int i = 0; i < MAXSTEPS / 64; i++) {
        const float t = t0 + (float)(k0 + i) * STEPSZ;
        if (t > tmax) break;

        float px = fminf(fmaxf(ox + t * dx, 0.0f), 127.0f);
        float py = fminf(fmaxf(oy + t * dy, 0.0f), 127.0f);
        float pz = fminf(fmaxf(oz + t * dz, 0.0f), 127.0f);
        const int lx = min(max((int)px, 0), 126);
        const int ly = min(max((int)py, 0), 126);
        const int lz = min(max((int)pz, 0), 126);
        const float fx = px - (float)lx;
        const float fy = py - (float)ly;
        const float fz = pz - (float)lz;

        const int cell = (lx << 14) | (ly << 7) | lz;
        if (cell != cached_cell) {
            cached_cell = cell;
            #pragma unroll
            for (int c = 0; c < 8; c++) {
                const int cdx = (c >> 2) & 1, cdy = (c >> 1) & 1, cdz = c & 1;
                const int idx = cell + (cdx << 14) + (cdy << 7) + cdz;
                const int lnk = links[idx];
                float sg = 0, q0 = 0, q1 = 0, q2 = 0;
                if (lnk >= 0) {
                    sg = density[lnk];
                    const float* row = sh + (size_t)lnk * 27;
                    #pragma unroll
                    for (int k = 0; k < 9; k++) {
                        const float m = shm[k];
                        q0 += m * row[k];
                        q1 += m * row[9 + k];
                        q2 += m * row[18 + k];
                    }
                }
                csig[c] = sg; cr0[c] = q0; cr1[c] = q1; cr2[c] = q2;
            }
        }

        const float gx1 = fx, gx0 = 1.0f - fx;
        const float gy1 = fy, gy0 = 1.0f - fy;
        const float gz1 = fz, gz0 = 1.0f - fz;
        float w[8];
        w[0] = gx0*gy0*gz0; w[1] = gx0*gy0*gz1; w[2] = gx0*gy1*gz0; w[3] = gx0*gy1*gz1;
        w[4] = gx1*gy0*gz0; w[5] = gx1*gy0*gz1; w[6] = gx1*gy1*gz0; w[7] = gx1*gy1*gz1;

        float sigma = 0, c0 = 0, c1 = 0, c2 = 0;
        #pragma unroll
        for (int c = 0; c < 8; c++) {
            sigma += w[c] * csig[c];
            c0    += w[c] * cr0[c];
            c1    += w[c] * cr1[c];
            c2    += w[c] * cr2[c];
        }

        const float la = -STEPSZ * fmaxf(sigma, 0.0f) * ds;
        const float e  = __expf(la);
        const float ws = light * (1.0f - e);
        c0 = fmaxf(c0 + 0.5f, 0.0f);
        c1 = fmaxf(c1 + 0.5f, 0.0f);
        c2 = fmaxf(c2 + 0.5f, 0.0f);

        aR += ws * c0; aG += ws * c1; aB += ws * c2;
        aA += ws;
        const float dd = t * ds;
        aD1 += ws * dd;
        aD2 += ws * dd * dd;
        light *= e;
        ll    += la;
    }

    float inc = ll;
    #pragma unroll
    for (int off = 1; off < 64; off <<= 1) {
        const float v = __shfl_up(inc, off, 64);
        if (lane >= off) inc += v;
    }
    const float pre = inc - ll;
    const float T   = __expf(pre);
    aR *= T; aG *= T; aB *= T; aA *= T; aD1 *= T; aD2 *= T;

    #pragma unroll
    for (int off = 32; off; off >>= 1) {
        aR  += __shfl_xor(aR,  off, 64);
        aG  += __shfl_xor(aG,  off, 64);
        aB  += __shfl_xor(aB,  off, 64);
        aA  += __shfl_xor(aA,  off, 64);
        aD1 += __shfl_xor(aD1, off, 64);
        aD2 += __shfl_xor(aD2, off, 64);
    }
    const float llt = __shfl(inc, 63, 64);

    if (lane == 0) {
        const float bg    = __expf(llt);
        const float denom = fmaxf(aA, 1e-10f);
        const float E     = aD1 / denom;
        const float ov    = aD2 - 2.0f * E * aD1 + E * E * aA;
        const int o = ray * 6;
        out[o + 0] = aR + bg;
        out[o + 1] = aG + bg;
        out[o + 2] = aB + bg;
        out[o + 3] = aA;
        out[o + 4] = E;
        out[o + 5] = ov / denom;
    }
}

extern "C" void kernel_launch(void* const* d_in, const int* in_sizes, int n_in,
                              void* d_out, int out_size, void* d_ws, size_t ws_size,
                              hipStream_t stream) {
    const float* origins = (const float*)d_in[0];
    const float* dirs    = (const float*)d_in[1];
    const int*   links   = (const int*)d_in[2];
    const float* density = (const float*)d_in[3];
    const float* sh      = (const float*)d_in[4];
    float* out = (float*)d_out;

    if (ws_size >= PACK_BYTES + part_bytes(32)) {
        _Float16* pack  = (_Float16*)d_ws;
        float*    parts = (float*)((char*)d_ws + PACK_BYTES);
        repack_kernel<<<dim3(NVOX / 256), dim3(256), 0, stream>>>(links, density, sh, pack);
        march_part_kernel<32><<<dim3(TILES * 32 / WPB), dim3(256), 0, stream>>>(
            origins, dirs, pack, parts);
        stitch_kernel<32><<<dim3(NRAYS / 256), dim3(256), 0, stream>>>(parts, out);
    } else if (ws_size >= PACK_BYTES + part_bytes(16)) {
        _Float16* pack  = (_Float16*)d_ws;
        float*    parts = (float*)((char*)d_ws + PACK_BYTES);
        repack_kernel<<<dim3(NVOX / 256), dim3(256), 0, stream>>>(links, density, sh, pack);
        march_part_kernel<16><<<dim3(TILES * 16 / WPB), dim3(256), 0, stream>>>(
            origins, dirs, pack, parts);
        stitch_kernel<16><<<dim3(NRAYS / 256), dim3(256), 0, stream>>>(parts, out);
    } else {
        march_fallback_kernel<<<dim3(NRAYS / 4), dim3(256), 0, stream>>>(
            origins, dirs, links, density, sh, out);
    }
}